// Round 3
// baseline (401.538 us; speedup 1.0000x reference)
//
#include <hip/hip_runtime.h>

#define N_NODES 100000
#define IN_F 256
#define OUT_F 128
#define NB 782        // row buckets of 128 rows
#define CAP 2560      // per-bucket edge capacity (mean 2048, sigma 45 -> 11 sigma headroom)
#define QCAP 896      // per-quarter (32-row) capacity (mean 512, sigma 22.6 -> 17 sigma)
#define TILE 4096     // edges per scatter block

typedef __attribute__((ext_vector_type(8))) short v8s;
typedef __attribute__((ext_vector_type(4))) float v4f;

__device__ __forceinline__ unsigned short f2bf(float f) {
    unsigned int u = __float_as_uint(f);
    u += 0x7fffu + ((u >> 16) & 1u);
    return (unsigned short)(u >> 16);
}
__device__ __forceinline__ float bf2f(unsigned short s) {
    return __uint_as_float((unsigned int)s << 16);
}

// weight [K=256][F=128] fp32 -> bt bf16 [F=128][K=256]
__global__ void wt_kernel(const float* __restrict__ w, unsigned short* __restrict__ bt) {
    int idx = blockIdx.x * 256 + threadIdx.x;
    int k = idx >> 7;
    int n = idx & 127;
    bt[n * IN_F + k] = f2bf(w[idx]);
}

// thin bf16 GEMM, fused dropout. NO LDS, NO barriers:
// A (x,u fp32) direct from global; B fragments direct from global (bt is 64KB,
// L2-hot, reused by all blocks). Depth-2 software pipeline on both operands ->
// ~12 loads in flight per wave, latency off the critical path.
// block = 64 rows x 128 cols, 4 independent waves of 16 rows.
__global__ __launch_bounds__(256) void gemm_kernel(
    const float* __restrict__ x, const float* __restrict__ u,
    const unsigned short* __restrict__ bt, unsigned short* __restrict__ support) {
    const int tid  = threadIdx.x;
    const int lane = tid & 63;
    const int wv   = tid >> 6;
    const int cl   = lane & 15;
    const int kq   = lane >> 4;          // 0..3 -> k-chunk of 8
    const long long row = (long long)blockIdx.x * 64 + wv * 16 + cl;
    const bool rv = row < N_NODES;
    const long long rowc = rv ? row : (N_NODES - 1);
    const float* xs = x + rowc * IN_F + kq * 8;
    const float* us = u + rowc * IN_F + kq * 8;
    const float m = rv ? 1.25f : 0.0f;   // folds OOB-row zeroing into dropout scale
    const unsigned short* bb = bt + cl * IN_F + kq * 8;  // + tn*16*IN_F + s*32

    v4f acc[8] = {};
    float4 xa0A, xa1A, ua0A, ua1A, xa0B, xa1B, ua0B, ua1B;
    v8s bfA[8], bfB[8];

#define LA(s, X0, X1, U0, U1) \
    X0 = *(const float4*)(xs + (s) * 32); \
    X1 = *(const float4*)(xs + (s) * 32 + 4); \
    U0 = *(const float4*)(us + (s) * 32); \
    U1 = *(const float4*)(us + (s) * 32 + 4)

#define LB(s, BF) \
    _Pragma("unroll") \
    for (int tn = 0; tn < 8; ++tn) \
        BF[tn] = *(const v8s*)(bb + tn * 16 * IN_F + (s) * 32)

#define STEP(s, X0, X1, U0, U1, BF) \
    { \
        float4 x0 = X0, x1 = X1, u0 = U0, u1 = U1; \
        v8s bf[8]; \
        _Pragma("unroll") \
        for (int tn = 0; tn < 8; ++tn) bf[tn] = BF[tn]; \
        if ((s) < 6) { LA((s) + 2, X0, X1, U0, U1); LB((s) + 2, BF); } \
        unsigned short t0 = f2bf(u0.x > 0.2f ? x0.x * m : 0.0f); \
        unsigned short t1 = f2bf(u0.y > 0.2f ? x0.y * m : 0.0f); \
        unsigned short t2 = f2bf(u0.z > 0.2f ? x0.z * m : 0.0f); \
        unsigned short t3 = f2bf(u0.w > 0.2f ? x0.w * m : 0.0f); \
        unsigned short t4 = f2bf(u1.x > 0.2f ? x1.x * m : 0.0f); \
        unsigned short t5 = f2bf(u1.y > 0.2f ? x1.y * m : 0.0f); \
        unsigned short t6 = f2bf(u1.z > 0.2f ? x1.z * m : 0.0f); \
        unsigned short t7 = f2bf(u1.w > 0.2f ? x1.w * m : 0.0f); \
        v8s af = {(short)t0, (short)t1, (short)t2, (short)t3, \
                  (short)t4, (short)t5, (short)t6, (short)t7}; \
        _Pragma("unroll") \
        for (int tn = 0; tn < 8; ++tn) \
            acc[tn] = __builtin_amdgcn_mfma_f32_16x16x32_bf16(af, bf[tn], acc[tn], 0, 0, 0); \
    }

    // prologue: fill both pipeline stages
    LA(0, xa0A, xa1A, ua0A, ua1A); LB(0, bfA);
    LA(1, xa0B, xa1B, ua0B, ua1B); LB(1, bfB);

    STEP(0, xa0A, xa1A, ua0A, ua1A, bfA);
    STEP(1, xa0B, xa1B, ua0B, ua1B, bfB);
    STEP(2, xa0A, xa1A, ua0A, ua1A, bfA);
    STEP(3, xa0B, xa1B, ua0B, ua1B, bfB);
    STEP(4, xa0A, xa1A, ua0A, ua1A, bfA);
    STEP(5, xa0B, xa1B, ua0B, ua1B, bfB);
    STEP(6, xa0A, xa1A, ua0A, ua1A, bfA);
    STEP(7, xa0B, xa1B, ua0B, ua1B, bfB);

#undef LA
#undef LB
#undef STEP

    const int rq = lane >> 4;
    #pragma unroll
    for (int r = 0; r < 4; ++r) {
        long long g = (long long)blockIdx.x * 64 + wv * 16 + rq * 4 + r;
        if (g < N_NODES) {
            unsigned short* o = support + g * OUT_F + cl;
            #pragma unroll
            for (int tn = 0; tn < 8; ++tn)
                o[tn * 16] = f2bf(acc[tn][r]);
        }
    }
}

__global__ void init_kernel(int* __restrict__ cursor) {
    int i = blockIdx.x * 256 + threadIdx.x;
    if (i < NB) cursor[i * 16] = i * CAP;   // 64B-padded cursors
}

// coalesced bucket scatter: tile -> LDS hist -> scan -> reserve -> reorder -> run writes
__global__ __launch_bounds__(256) void scatter_kernel(
    const int* __restrict__ row, const int* __restrict__ col,
    const float* __restrict__ val, int* __restrict__ cursor,
    int2* __restrict__ cv, int E) {
    __shared__ int cnt[1024];
    __shared__ int loc[1024];
    __shared__ int delta[1024];
    __shared__ int tmp[256];
    __shared__ int gd[TILE];
    __shared__ int2 stage[TILE];
    __shared__ int total_s;
    const int tid = threadIdx.x;
    const int base_e = blockIdx.x * TILE;

    for (int i = tid; i < 1024; i += 256) cnt[i] = 0;
    __syncthreads();
    #pragma unroll
    for (int j = 0; j < TILE / 256; ++j) {
        int e = base_e + j * 256 + tid;
        if (e < E) atomicAdd(&cnt[row[e] >> 7], 1);
    }
    __syncthreads();
    int c0 = cnt[4*tid], c1 = cnt[4*tid+1], c2 = cnt[4*tid+2], c3 = cnt[4*tid+3];
    int s = c0 + c1 + c2 + c3;
    tmp[tid] = s;
    __syncthreads();
    #pragma unroll
    for (int d = 1; d < 256; d <<= 1) {
        int t = (tid >= d) ? tmp[tid - d] : 0;
        __syncthreads();
        tmp[tid] += t;
        __syncthreads();
    }
    int excl = tmp[tid] - s;
    loc[4*tid]   = excl;
    loc[4*tid+1] = excl + c0;
    loc[4*tid+2] = excl + c0 + c1;
    loc[4*tid+3] = excl + c0 + c1 + c2;
    if (tid == 255) total_s = tmp[255];
    __syncthreads();
    for (int i = tid; i < NB; i += 256) {
        int c = cnt[i];
        int gbase = 0;
        if (c > 0) gbase = atomicAdd(&cursor[i * 16], c);
        delta[i] = gbase - loc[i];
        cnt[i] = loc[i];
    }
    __syncthreads();
    #pragma unroll
    for (int j = 0; j < TILE / 256; ++j) {
        int e = base_e + j * 256 + tid;
        if (e < E) {
            int r = row[e];
            int b = r >> 7;
            int rank = atomicAdd(&cnt[b], 1);
            stage[rank] = make_int2(col[e] | ((r & 127) << 17), __float_as_int(val[e]));
            gd[rank] = delta[b] + rank;
        }
    }
    __syncthreads();
    int total = total_s;
    for (int i = tid; i < total; i += 256)
        cv[gd[i]] = stage[i];
}

// per-QUARTER-bucket (32 rows): single cv scan with register-held edges,
// LDS counting-sort by local row, then csr-style register-accumulate gather
// with 8-deep load pipeline.
__global__ __launch_bounds__(256) void acc2_kernel(
    const int* __restrict__ cursor, const int2* __restrict__ cv,
    const unsigned short* __restrict__ support, float* __restrict__ out) {
    __shared__ int2 sorted[QCAP];    // 7168 B
    __shared__ int cnt_s[32];
    __shared__ int start_s[32];
    __shared__ int pos_s[32];
    const int tid = threadIdx.x;
    const int bq = blockIdx.x;
    const int b = bq >> 2;          // source 128-row bucket
    const int q = bq & 3;           // quarter: rows q*32 .. q*32+31
    const int e0 = b * CAP;
    const int nE = cursor[b * 16] - e0;

    if (tid < 32) cnt_s[tid] = 0;
    __syncthreads();
    // single pass: histogram + hold this quarter's edges in fixed register slots
    int2 ej[10];
    int  vj[10];                    // local row (0..31) if mine, else -1
    #pragma unroll
    for (int j = 0; j < 10; ++j) {  // 10*256 = 2560 = CAP, always in-bounds
        int i = j * 256 + tid;
        int2 c = cv[e0 + i];
        int lr = (c.x >> 17) & 127;
        int mine = (i < nE) && ((lr >> 5) == q);
        ej[j] = c;
        vj[j] = mine ? (lr & 31) : -1;
        if (mine) atomicAdd(&cnt_s[lr & 31], 1);
    }
    __syncthreads();
    // scan 32 bins with a single-wave shfl scan
    if (tid < 32) {
        int v = cnt_s[tid];
        int sc = v;
        #pragma unroll
        for (int d = 1; d < 32; d <<= 1) {
            int t = __shfl_up(sc, d, 64);
            if (tid >= d) sc += t;
        }
        start_s[tid] = sc - v;
        pos_s[tid] = sc - v;
    }
    __syncthreads();
    // place held edges into row-sorted LDS
    #pragma unroll
    for (int j = 0; j < 10; ++j) {
        if (vj[j] >= 0) {
            int rank = atomicAdd(&pos_s[vj[j]], 1);
            sorted[rank] = ej[j];
        }
    }
    __syncthreads();
    // gather: wave w owns rows w*8 .. w*8+7; 8 loads in flight, one write/row
    const int lane = tid & 63, w = tid >> 6;
    const long long rowbase = (long long)b * 128 + q * 32;
    for (int rr = 0; rr < 8; ++rr) {
        int rl = w * 8 + rr;
        int e = start_s[rl];
        int end = e + cnt_s[rl];
        float a0 = 0.f, a1 = 0.f;
        for (; e < end; e += 8) {
            #pragma unroll
            for (int j = 0; j < 8; ++j) {
                int idx = e + j;
                int ids = min(idx, end - 1);
                int2 c = sorted[ids];
                float vv = (idx < end) ? __int_as_float(c.y) : 0.0f;
                int colv = c.x & 131071;
                unsigned int uu = *(const unsigned int*)(support + colv * OUT_F + lane * 2);
                a0 = fmaf(vv, bf2f((unsigned short)(uu & 0xffff)), a0);
                a1 = fmaf(vv, bf2f((unsigned short)(uu >> 16)), a1);
            }
        }
        long long g = rowbase + rl;
        if (g < N_NODES)
            *(float2*)(out + g * OUT_F + lane * 2) = make_float2(a0, a1);
    }
}

extern "C" void kernel_launch(void* const* d_in, const int* in_sizes, int n_in,
                              void* d_out, int out_size, void* d_ws, size_t ws_size,
                              hipStream_t stream) {
    const float* input   = (const float*)d_in[0];
    const float* weight  = (const float*)d_in[1];
    const int*   adj_row = (const int*)d_in[2];
    const int*   adj_col = (const int*)d_in[3];
    const float* adj_val = (const float*)d_in[4];
    const float* drop_u  = (const float*)d_in[5];
    float* out = (float*)d_out;
    const int E = in_sizes[2];

    // ws layout: bt 64K | cv int2 16M | support bf16 25.6M | cursor 50K
    char* p = (char*)d_ws;
    unsigned short* bt      = (unsigned short*)p;  p += 65536;
    int2*           cv      = (int2*)p;            p += (size_t)NB * CAP * sizeof(int2);
    unsigned short* support = (unsigned short*)p;  p += (size_t)N_NODES * OUT_F * 2;
    int*            cursor  = (int*)p;

    init_kernel<<<4, 256, 0, stream>>>(cursor);
    wt_kernel<<<128, 256, 0, stream>>>(weight, bt);
    gemm_kernel<<<(N_NODES + 63) / 64, 256, 0, stream>>>(input, drop_u, bt, support);
    scatter_kernel<<<(E + TILE - 1) / TILE, 256, 0, stream>>>(adj_row, adj_col, adj_val, cursor, cv, E);
    acc2_kernel<<<NB * 4, 256, 0, stream>>>(cursor, cv, support, out);
}

// Round 4
// 373.676 us; speedup vs baseline: 1.0746x; 1.0746x over previous
//
#include <hip/hip_runtime.h>

#define N_NODES 100000
#define IN_F 256
#define OUT_F 128
#define NB 782        // row buckets of 128 rows
#define CAP 2560      // per-bucket edge capacity (mean 2048, sigma 45 -> 11 sigma headroom)
#define QCAP 896      // per-quarter (32-row) capacity (mean 512, sigma 22.6 -> 17 sigma)
#define TILE 4096     // edges per scatter block
#define ASTR 264      // As leading dim (shorts): 264*2=528B = 132 words = 4 mod 32 -> even b128 spread

typedef __attribute__((ext_vector_type(8))) short v8s;
typedef __attribute__((ext_vector_type(4))) float v4f;

__device__ __forceinline__ unsigned short f2bf(float f) {
    unsigned int u = __float_as_uint(f);
    u += 0x7fffu + ((u >> 16) & 1u);
    return (unsigned short)(u >> 16);
}
__device__ __forceinline__ float bf2f(unsigned short s) {
    return __uint_as_float((unsigned int)s << 16);
}

// weight [K=256][F=128] fp32 -> wave-fragment-linear bf16 table:
// element [col][k] (col=tn*16+cl, k=s*32+kq*8+i) stored at ((tn*8+s)*64 + kq*16+cl)*8 + i
// so gemm's per-(tn,s) B-load is one contiguous 1KB wave read.
__global__ void wt_kernel(const float* __restrict__ w, unsigned short* __restrict__ bt) {
    int idx = blockIdx.x * 256 + threadIdx.x;   // 32768
    int k   = idx >> 7;
    int col = idx & 127;
    int tn = col >> 4, cl = col & 15;
    int s = k >> 5, kq = (k >> 3) & 3, i = k & 7;
    bt[((tn * 8 + s) * 64 + kq * 16 + cl) * 8 + i] = f2bf(w[idx]);
}

// thin bf16 GEMM, fused dropout.
// Stage: block reads its FULL 64-row x/u panel as one dense contiguous region
// (lane-contiguous float4s -> DRAM-page-friendly), dropout in regs, bf16 -> LDS.
// One barrier. Then: per-wave A panel cached in 8 v8s regs; 8 column phases,
// B frags direct from L2-hot fragment-linear table (1KB contiguous per load),
// double-buffered one phase ahead. Zero loop barriers, zero loop LDS traffic.
__global__ __launch_bounds__(256) void gemm_kernel(
    const float* __restrict__ x, const float* __restrict__ u,
    const unsigned short* __restrict__ bt, unsigned short* __restrict__ support) {
    __shared__ unsigned short As[64 * ASTR];
    const int tid  = threadIdx.x;
    const int lane = tid & 63;
    const int wv   = tid >> 6;
    const int cl   = lane & 15;
    const int kq   = lane >> 4;
    const long long base = (long long)blockIdx.x * 64;

    {   // ---- stage A: 4096 float4 of x + 4096 of u, contiguous across the block
        const float4* x4 = (const float4*)(x + base * IN_F);
        const float4* u4 = (const float4*)(u + base * IN_F);
        const int fc = (tid & 63) * 4;          // float offset within row
        #pragma unroll
        for (int j = 0; j < 16; ++j) {
            const int row = j * 4 + (tid >> 6); // (tid + j*256)/64
            const bool ok = (base + row) < N_NODES;
            float4 xi = ok ? x4[j * 256 + tid] : make_float4(0.f, 0.f, 0.f, 0.f);
            float4 du = ok ? u4[j * 256 + tid] : make_float4(0.f, 0.f, 0.f, 0.f);
            ushort4 pk;
            pk.x = f2bf(du.x > 0.2f ? xi.x * 1.25f : 0.0f);
            pk.y = f2bf(du.y > 0.2f ? xi.y * 1.25f : 0.0f);
            pk.z = f2bf(du.z > 0.2f ? xi.z * 1.25f : 0.0f);
            pk.w = f2bf(du.w > 0.2f ? xi.w * 1.25f : 0.0f);
            *(ushort4*)(&As[row * ASTR + fc]) = pk;
        }
    }
    __syncthreads();

    // ---- wave's full A panel -> 8 v8s (32 VGPR), reused by all 8 phases
    v8s a[8];
    #pragma unroll
    for (int s = 0; s < 8; ++s)
        a[s] = *(const v8s*)&As[(wv * 16 + cl) * ASTR + s * 32 + kq * 8];

    const v8s* bp = (const v8s*)bt + lane;      // + (tn*8+s)*64
    const int rq = lane >> 4;
    v8s bA[8], bB[8];
    #pragma unroll
    for (int s = 0; s < 8; ++s) bA[s] = bp[s * 64];

#define PHASE(tn, BC, BN) { \
    if ((tn) < 7) { \
        _Pragma("unroll") \
        for (int s = 0; s < 8; ++s) BN[s] = bp[((tn) + 1) * 512 + s * 64]; \
    } \
    v4f acc = {0.f, 0.f, 0.f, 0.f}; \
    _Pragma("unroll") \
    for (int s = 0; s < 8; ++s) \
        acc = __builtin_amdgcn_mfma_f32_16x16x32_bf16(a[s], BC[s], acc, 0, 0, 0); \
    _Pragma("unroll") \
    for (int r = 0; r < 4; ++r) { \
        long long g = base + wv * 16 + rq * 4 + r; \
        if (g < N_NODES) \
            support[g * OUT_F + (tn) * 16 + cl] = f2bf(acc[r]); \
    } }

    PHASE(0, bA, bB)
    PHASE(1, bB, bA)
    PHASE(2, bA, bB)
    PHASE(3, bB, bA)
    PHASE(4, bA, bB)
    PHASE(5, bB, bA)
    PHASE(6, bA, bB)
    PHASE(7, bB, bA)
#undef PHASE
}

__global__ void init_kernel(int* __restrict__ cursor) {
    int i = blockIdx.x * 256 + threadIdx.x;
    if (i < NB) cursor[i * 16] = i * CAP;   // 64B-padded cursors
}

// coalesced bucket scatter: tile -> LDS hist -> scan -> reserve -> reorder -> run writes
__global__ __launch_bounds__(256) void scatter_kernel(
    const int* __restrict__ row, const int* __restrict__ col,
    const float* __restrict__ val, int* __restrict__ cursor,
    int2* __restrict__ cv, int E) {
    __shared__ int cnt[1024];
    __shared__ int loc[1024];
    __shared__ int delta[1024];
    __shared__ int tmp[256];
    __shared__ int gd[TILE];
    __shared__ int2 stage[TILE];
    __shared__ int total_s;
    const int tid = threadIdx.x;
    const int base_e = blockIdx.x * TILE;

    for (int i = tid; i < 1024; i += 256) cnt[i] = 0;
    __syncthreads();
    #pragma unroll
    for (int j = 0; j < TILE / 256; ++j) {
        int e = base_e + j * 256 + tid;
        if (e < E) atomicAdd(&cnt[row[e] >> 7], 1);
    }
    __syncthreads();
    int c0 = cnt[4*tid], c1 = cnt[4*tid+1], c2 = cnt[4*tid+2], c3 = cnt[4*tid+3];
    int s = c0 + c1 + c2 + c3;
    tmp[tid] = s;
    __syncthreads();
    #pragma unroll
    for (int d = 1; d < 256; d <<= 1) {
        int t = (tid >= d) ? tmp[tid - d] : 0;
        __syncthreads();
        tmp[tid] += t;
        __syncthreads();
    }
    int excl = tmp[tid] - s;
    loc[4*tid]   = excl;
    loc[4*tid+1] = excl + c0;
    loc[4*tid+2] = excl + c0 + c1;
    loc[4*tid+3] = excl + c0 + c1 + c2;
    if (tid == 255) total_s = tmp[255];
    __syncthreads();
    for (int i = tid; i < NB; i += 256) {
        int c = cnt[i];
        int gbase = 0;
        if (c > 0) gbase = atomicAdd(&cursor[i * 16], c);
        delta[i] = gbase - loc[i];
        cnt[i] = loc[i];
    }
    __syncthreads();
    #pragma unroll
    for (int j = 0; j < TILE / 256; ++j) {
        int e = base_e + j * 256 + tid;
        if (e < E) {
            int r = row[e];
            int b = r >> 7;
            int rank = atomicAdd(&cnt[b], 1);
            stage[rank] = make_int2(col[e] | ((r & 127) << 17), __float_as_int(val[e]));
            gd[rank] = delta[b] + rank;
        }
    }
    __syncthreads();
    int total = total_s;
    for (int i = tid; i < total; i += 256)
        cv[gd[i]] = stage[i];
}

// per-QUARTER-bucket (32 rows): single cv scan with register-held edges,
// LDS counting-sort by local row, then csr-style register-accumulate gather
// with 8-deep load pipeline.
__global__ __launch_bounds__(256) void acc2_kernel(
    const int* __restrict__ cursor, const int2* __restrict__ cv,
    const unsigned short* __restrict__ support, float* __restrict__ out) {
    __shared__ int2 sorted[QCAP];    // 7168 B
    __shared__ int cnt_s[32];
    __shared__ int start_s[32];
    __shared__ int pos_s[32];
    const int tid = threadIdx.x;
    const int bq = blockIdx.x;
    const int b = bq >> 2;          // source 128-row bucket
    const int q = bq & 3;           // quarter: rows q*32 .. q*32+31
    const int e0 = b * CAP;
    const int nE = cursor[b * 16] - e0;

    if (tid < 32) cnt_s[tid] = 0;
    __syncthreads();
    // single pass: histogram + hold this quarter's edges in fixed register slots
    int2 ej[10];
    int  vj[10];                    // local row (0..31) if mine, else -1
    #pragma unroll
    for (int j = 0; j < 10; ++j) {  // 10*256 = 2560 = CAP, always in-bounds
        int i = j * 256 + tid;
        int2 c = cv[e0 + i];
        int lr = (c.x >> 17) & 127;
        int mine = (i < nE) && ((lr >> 5) == q);
        ej[j] = c;
        vj[j] = mine ? (lr & 31) : -1;
        if (mine) atomicAdd(&cnt_s[lr & 31], 1);
    }
    __syncthreads();
    // scan 32 bins with a single-wave shfl scan
    if (tid < 32) {
        int v = cnt_s[tid];
        int sc = v;
        #pragma unroll
        for (int d = 1; d < 32; d <<= 1) {
            int t = __shfl_up(sc, d, 64);
            if (tid >= d) sc += t;
        }
        start_s[tid] = sc - v;
        pos_s[tid] = sc - v;
    }
    __syncthreads();
    // place held edges into row-sorted LDS
    #pragma unroll
    for (int j = 0; j < 10; ++j) {
        if (vj[j] >= 0) {
            int rank = atomicAdd(&pos_s[vj[j]], 1);
            sorted[rank] = ej[j];
        }
    }
    __syncthreads();
    // gather: wave w owns rows w*8 .. w*8+7; 8 loads in flight, one write/row
    const int lane = tid & 63, w = tid >> 6;
    const long long rowbase = (long long)b * 128 + q * 32;
    for (int rr = 0; rr < 8; ++rr) {
        int rl = w * 8 + rr;
        int e = start_s[rl];
        int end = e + cnt_s[rl];
        float a0 = 0.f, a1 = 0.f;
        for (; e < end; e += 8) {
            #pragma unroll
            for (int j = 0; j < 8; ++j) {
                int idx = e + j;
                int ids = min(idx, end - 1);
                int2 c = sorted[ids];
                float vv = (idx < end) ? __int_as_float(c.y) : 0.0f;
                int colv = c.x & 131071;
                unsigned int uu = *(const unsigned int*)(support + colv * OUT_F + lane * 2);
                a0 = fmaf(vv, bf2f((unsigned short)(uu & 0xffff)), a0);
                a1 = fmaf(vv, bf2f((unsigned short)(uu >> 16)), a1);
            }
        }
        long long g = rowbase + rl;
        if (g < N_NODES)
            *(float2*)(out + g * OUT_F + lane * 2) = make_float2(a0, a1);
    }
}

extern "C" void kernel_launch(void* const* d_in, const int* in_sizes, int n_in,
                              void* d_out, int out_size, void* d_ws, size_t ws_size,
                              hipStream_t stream) {
    const float* input   = (const float*)d_in[0];
    const float* weight  = (const float*)d_in[1];
    const int*   adj_row = (const int*)d_in[2];
    const int*   adj_col = (const int*)d_in[3];
    const float* adj_val = (const float*)d_in[4];
    const float* drop_u  = (const float*)d_in[5];
    float* out = (float*)d_out;
    const int E = in_sizes[2];

    // ws layout: bt 64K | cv int2 16M | support bf16 25.6M | cursor 50K
    char* p = (char*)d_ws;
    unsigned short* bt      = (unsigned short*)p;  p += 65536;
    int2*           cv      = (int2*)p;            p += (size_t)NB * CAP * sizeof(int2);
    unsigned short* support = (unsigned short*)p;  p += (size_t)N_NODES * OUT_F * 2;
    int*            cursor  = (int*)p;

    init_kernel<<<4, 256, 0, stream>>>(cursor);
    wt_kernel<<<128, 256, 0, stream>>>(weight, bt);
    gemm_kernel<<<(N_NODES + 63) / 64, 256, 0, stream>>>(input, drop_u, bt, support);
    scatter_kernel<<<(E + TILE - 1) / TILE, 256, 0, stream>>>(adj_row, adj_col, adj_val, cursor, cv, E);
    acc2_kernel<<<NB * 4, 256, 0, stream>>>(cursor, cv, support, out);
}